// Round 2
// baseline (137.137 us; speedup 1.0000x reference)
//
#include <hip/hip_runtime.h>
#include <hip/hip_bf16.h>

// SAGAN self-attention, MI355X gfx950. B=4, C=64, H=W=128, N=16384, M=4096.
// fp32 in/out. Round 12 (resubmit after infra failure): attn rework —
// (a) softmax denominator l moved from VALU adds to the MFMA pipe via an
// all-ones A-fragment (P is summed in the same bf16 the PV numerator
// consumes -> self-consistent softmax);
// (b) 4 waves x 32 n per wave (256-thr blocks, grid 512): F/G ds_reads and
// address math amortize over 2x work, halving the 8-way-redundant LDS read
// traffic. Layouts unchanged from the verified round-10/11 kernel:
// A[row=lane&15][k=8q+j(K32)/4q+j(K16)], B same k-map col=lane&15,
// C/D[row=4q+r][col=lane&15].

typedef __attribute__((ext_vector_type(4))) float f32x4;
typedef __attribute__((ext_vector_type(8))) short s16x8;
typedef __attribute__((ext_vector_type(4))) short s16x4;

__device__ __forceinline__ unsigned short f32_bf16(float f) {
    unsigned int u = __float_as_uint(f);
    return (unsigned short)((u + 0x7fffu + ((u >> 16) & 1u)) >> 16);  // RNE
}
__device__ __forceinline__ unsigned int pk_bf16(float a, float b) {
    return (unsigned int)f32_bf16(a) | ((unsigned int)f32_bf16(b) << 16);
}
__device__ __forceinline__ unsigned int pk_rh(float a, float b) {   // round-half-up
    unsigned int au = __float_as_uint(a) + 0x8000u;
    unsigned int bu = __float_as_uint(b) + 0x8000u;
    return __builtin_amdgcn_perm(bu, au, 0x07060302u);
}
__device__ __forceinline__ unsigned int pk_tr(float a, float b) {   // truncate
    return __builtin_amdgcn_perm(__float_as_uint(b), __float_as_uint(a), 0x07060302u);
}
// async 16B/lane global->LDS DMA; lds dest = wave-uniform base + lane*16
__device__ __forceinline__ void async16(const void* g, void* l) {
    __builtin_amdgcn_global_load_lds(
        (const __attribute__((address_space(1))) unsigned int*)g,
        (__attribute__((address_space(3))) unsigned int*)l, 16, 0, 0);
}

// ---------------- proj: theta/phi/g 1x1 conv + 2x2 maxpool, MFMA ----------------
// (verbatim round 10 — passed; emits pi-permuted gG)
__global__ __launch_bounds__(256) void proj_kernel(
    const float* __restrict__ x,
    const float* __restrict__ w_theta, const float* __restrict__ w_phi,
    const float* __restrict__ w_g,
    __hip_bfloat16* __restrict__ thG,   // [b][n][8]  (theta * log2e)
    __hip_bfloat16* __restrict__ phG,   // [b][m][8]
    __hip_bfloat16* __restrict__ gG)    // [b][32][4096], pi-permuted per 32-m chunk
{
    __shared__ __align__(16) unsigned short x_s[128 * 72];  // [pix][c], 144 B rows
    int tid = threadIdx.x;
    int bx = blockIdx.x;
    int b = bx >> 7, mh = (bx >> 1) & 63, ph = bx & 1;

    {   // phase 1: float4 loads (c-pair per thread), packed u32 LDS transpose
        int cp = tid >> 3, s = tid & 7;
        const float* xb = x + ((size_t)b << 20) + (size_t)(2 * mh) * 128 + 64 * ph;
        const float* p0r = xb + ((size_t)(2 * cp) << 14);
        const float* p1r = p0r + (1 << 14);
#pragma unroll
        for (int py = 0; py < 2; py++)
#pragma unroll
            for (int t = 0; t < 2; t++) {
                int pxl = 4 * s + 32 * t;
                float4 a = *(const float4*)(p0r + py * 128 + pxl);
                float4 c = *(const float4*)(p1r + py * 128 + pxl);
                int pix = py * 64 + pxl;
                *(unsigned int*)&x_s[(pix + 0) * 72 + 2 * cp] = pk_rh(a.x, c.x);
                *(unsigned int*)&x_s[(pix + 1) * 72 + 2 * cp] = pk_rh(a.y, c.y);
                *(unsigned int*)&x_s[(pix + 2) * 72 + 2 * cp] = pk_rh(a.z, c.z);
                *(unsigned int*)&x_s[(pix + 3) * 72 + 2 * cp] = pk_rh(a.w, c.w);
            }
    }

    int lane = tid & 63, w = tid >> 6;
    int q = lane >> 4, nl = lane & 15;

    s16x8 A[3][2];
#pragma unroll
    for (int CT = 0; CT < 3; CT++) {
        const float* wsrc;
        float scale = 1.0f;
        if (CT == 0) {
            if (nl < 8) { wsrc = w_theta + nl * 64; scale = 1.44269504f; }
            else        { wsrc = w_phi + (nl - 8) * 64; }
        } else if (CT == 1) wsrc = w_g + nl * 64;
        else                wsrc = w_g + (16 + nl) * 64;
#pragma unroll
        for (int ks = 0; ks < 2; ks++) {
            const float4* p4 = (const float4*)(wsrc + 32 * ks + 8 * q);
            float4 a0 = p4[0], a1 = p4[1];
            s16x8 f;
            f[0] = (short)f32_bf16(a0.x * scale); f[1] = (short)f32_bf16(a0.y * scale);
            f[2] = (short)f32_bf16(a0.z * scale); f[3] = (short)f32_bf16(a0.w * scale);
            f[4] = (short)f32_bf16(a1.x * scale); f[5] = (short)f32_bf16(a1.y * scale);
            f[6] = (short)f32_bf16(a1.z * scale); f[7] = (short)f32_bf16(a1.w * scale);
            A[CT][ks] = f;
        }
    }
    __syncthreads();

    f32x4 acc[3][2];
#pragma unroll
    for (int ti = 0; ti < 2; ti++) {
        int tile = w + 4 * ti;
        const unsigned short* rb = x_s + (16 * tile + nl) * 72;
        s16x8 B0 = *(const s16x8*)(rb + 8 * q);
        s16x8 B1 = *(const s16x8*)(rb + 32 + 8 * q);
#pragma unroll
        for (int CT = 0; CT < 3; CT++) {
            f32x4 d = (f32x4){0.f, 0.f, 0.f, 0.f};
            d = __builtin_amdgcn_mfma_f32_16x16x32_bf16(A[CT][0], B0, d, 0, 0, 0);
            d = __builtin_amdgcn_mfma_f32_16x16x32_bf16(A[CT][1], B1, d, 0, 0, 0);
            acc[CT][ti] = d;
        }
    }

    if (q < 2) {
        unsigned short* thb = (unsigned short*)thG + ((size_t)b << 14) * 8;
#pragma unroll
        for (int ti = 0; ti < 2; ti++) {
            int n = (2 * mh + ti) * 128 + 64 * ph + 16 * w + nl;
            uint2 tv;
            tv.x = pk_bf16(acc[0][ti][0], acc[0][ti][1]);
            tv.y = pk_bf16(acc[0][ti][2], acc[0][ti][3]);
            *(uint2*)(thb + (size_t)n * 8 + 4 * q) = tv;
        }
    }

    float pool[3][4];
#pragma unroll
    for (int CT = 0; CT < 3; CT++)
#pragma unroll
        for (int r = 0; r < 4; r++) {
            float a = fmaxf(acc[CT][0][r], acc[CT][1][r]);
            pool[CT][r] = fmaxf(a, __shfl_xor(a, 1));
        }

    int mm = 8 * w + (nl >> 1);
    int mbase = mh * 64 + ph * 32;
    if ((nl & 1) == 0) {
        if (q >= 2) {
            uint2 pv;
            pv.x = pk_bf16(pool[0][0], pool[0][1]);
            pv.y = pk_bf16(pool[0][2], pool[0][3]);
            *(uint2*)((unsigned short*)phG + ((size_t)(b * 4096 + mbase + mm)) * 8 + (q - 2) * 4) = pv;
        }
        int p = 8 * ((mm >> 2) & 3) + 4 * ((mm >> 4) & 1) + (mm & 3);
        int mstore = mbase + p;
#pragma unroll
        for (int CT = 1; CT < 3; CT++)
#pragma unroll
            for (int r = 0; r < 4; r++) {
                int cg = 16 * (CT - 1) + 4 * q + r;
                ((unsigned short*)gG)[((size_t)(b * 32 + cg) << 12) + mstore] =
                    f32_bf16(pool[CT][r]);
            }
    }
}

// ---------------- attn: K32 score -> exp2 -> K16 PV, l via ones-MFMA ----------------
// Grid 512 = b(4) x n-tile(128). Block 256 thr = 4 waves x 32 n each, full m.
// LDS: g dbuf 2x16384 (rows GROW=512B, XOR-swizzled slots) + phi dbuf 2x4096.
__global__ __launch_bounds__(256) void attn_kernel(
    const __hip_bfloat16* __restrict__ thG, const __hip_bfloat16* __restrict__ phG,
    const __hip_bfloat16* __restrict__ gG,
    const float* __restrict__ w_o, const float* __restrict__ gamma,
    const float* __restrict__ x, float* __restrict__ out)
{
    __shared__ __align__(16) unsigned char smem[2 * 16384 + 2 * 4096];  // 40960 B
    unsigned char* O_s = smem;   // epilogue overlay [128][80 B] (g buf0 region)

    int tid = threadIdx.x, lane = tid & 63, w = tid >> 6;   // w: 0..3
    int q = lane >> 4, nl = lane & 15;
    int bx = blockIdx.x;
    int b  = bx >> 7;
    int n0 = (bx & 127) << 7;
    int nw = n0 + w * 32;

    const unsigned short* thb = (const unsigned short*)thG + ((size_t)b << 14) * 8;
    const unsigned short* phb = (const unsigned short*)phG + ((size_t)b << 12) * 8;
    const unsigned short* ggb = (const unsigned short*)gG + ((size_t)b << 17);

    // theta B-frags (K32), 2 n-frags per wave: B[k=c=8q+j][col=n=nl]
    s16x8 BT0 = (s16x8){0, 0, 0, 0, 0, 0, 0, 0};
    s16x8 BT1 = (s16x8){0, 0, 0, 0, 0, 0, 0, 0};
    if (q == 0) {
        BT0 = *(const s16x8*)(thb + (size_t)(nw + nl) * 8);
        BT1 = *(const s16x8*)(thb + (size_t)(nw + 16 + nl) * 8);
    } else if (q == 1) {
        BT0[0] = (short)0xC167;   // bf16(-14.4375) bias k-slot
        BT1[0] = (short)0xC167;
    }
    // phi A-frag const part: q1/j0 -> k=8 slot = 1.0
    s16x8 Fc = (s16x8){0, 0, 0, 0, 0, 0, 0, 0};
    if (q == 1) Fc[0] = (short)0x3F80;
    // all-ones K16 A-frag for the denominator MFMA (layout-independent)
    const s16x4 ONE4 = (s16x4){(short)0x3F80, (short)0x3F80, (short)0x3F80, (short)0x3F80};

    f32x4 acc00 = (f32x4){0.f, 0.f, 0.f, 0.f};   // c 0..15,  nf0
    f32x4 acc10 = (f32x4){0.f, 0.f, 0.f, 0.f};   // c 16..31, nf0
    f32x4 acc01 = (f32x4){0.f, 0.f, 0.f, 0.f};   // c 0..15,  nf1
    f32x4 acc11 = (f32x4){0.f, 0.f, 0.f, 0.f};   // c 16..31, nf1
    f32x4 accL0 = (f32x4){0.f, 0.f, 0.f, 0.f};   // sum_m P, nf0 (rows identical)
    f32x4 accL1 = (f32x4){0.f, 0.f, 0.f, 0.f};   // sum_m P, nf1

    // async staging: wave w stages g rows 8w..8w+7 (4 calls, 2 rows each);
    // lane i -> LDS slot i&31 of row (i>>5); source slot = (i&31) XOR row.
    int r0 = 8 * w + (lane >> 5);
    const unsigned short* gsrc0 = ggb + ((size_t)(r0 + 0) << 12) + 8 * ((lane & 31) ^ (r0 + 0));
    const unsigned short* gsrc1 = ggb + ((size_t)(r0 + 2) << 12) + 8 * ((lane & 31) ^ (r0 + 2));
    const unsigned short* gsrc2 = ggb + ((size_t)(r0 + 4) << 12) + 8 * ((lane & 31) ^ (r0 + 4));
    const unsigned short* gsrc3 = ggb + ((size_t)(r0 + 6) << 12) + 8 * ((lane & 31) ^ (r0 + 6));
    const unsigned short* psrc  = phb + (size_t)(w * 64 + lane) * 8;
    unsigned char* ldsg0 = smem + w * 4096;            // + buf*16384
    unsigned char* ldsg1 = ldsg0 + 1024;
    unsigned char* ldsg2 = ldsg0 + 2048;
    unsigned char* ldsg3 = ldsg0 + 3072;
    unsigned char* ldsp  = smem + 32768 + w * 1024;    // + buf*4096

    // pre-stage st 0 -> buf 0
    async16(gsrc0, ldsg0);
    async16(gsrc1, ldsg1);
    async16(gsrc2, ldsg2);
    async16(gsrc3, ldsg3);
    async16(psrc, ldsp);
    __syncthreads();

    for (int st = 0; st < 16; st++) {
        const unsigned char* gcur = smem + (st & 1) * 16384;
        const unsigned char* pcur = smem + 32768 + (st & 1) * 4096;
        if (st < 15) {   // issue next st's DMA into the other buffers (no wait)
            int mo = (st + 1) << 8;           // g element offset (256/st)
            int nb = (st + 1) & 1;
            async16(gsrc0 + mo, ldsg0 + nb * 16384);
            async16(gsrc1 + mo, ldsg1 + nb * 16384);
            async16(gsrc2 + mo, ldsg2 + nb * 16384);
            async16(gsrc3 + mo, ldsg3 + nb * 16384);
            async16(psrc + (size_t)mo * 8, ldsp + nb * 4096);
        }
#pragma unroll
        for (int cc = 0; cc < 8; cc++) {
            int mloc = cc << 5;
            s16x8 F0 = Fc, F1 = Fc;
            if (q == 0) {   // phi A-frags from LDS (linear rows, 4-way broadcast)
                F0 = *(const s16x8*)(pcur + (mloc + nl) * 16);
                F1 = *(const s16x8*)(pcur + (mloc + 16 + nl) * 16);
            }
            // issue g reads early; pi-permuted g, XOR-swizzled slots
            int t = (cc << 2) + q;
            s16x8 G0 = *(const s16x8*)(gcur + nl * 512 + ((t ^ nl) << 4));
            s16x8 G1 = *(const s16x8*)(gcur + (nl + 16) * 512 + ((t ^ (nl + 16)) << 4));

            f32x4 z = (f32x4){0.f, 0.f, 0.f, 0.f};
            f32x4 s00 = __builtin_amdgcn_mfma_f32_16x16x32_bf16(F0, BT0, z, 0, 0, 0);
            f32x4 s01 = __builtin_amdgcn_mfma_f32_16x16x32_bf16(F1, BT0, z, 0, 0, 0);
            f32x4 s10 = __builtin_amdgcn_mfma_f32_16x16x32_bf16(F0, BT1, z, 0, 0, 0);
            f32x4 s11 = __builtin_amdgcn_mfma_f32_16x16x32_bf16(F1, BT1, z, 0, 0, 0);

            float a0 = __builtin_amdgcn_exp2f(s00[0]);
            float a1 = __builtin_amdgcn_exp2f(s00[1]);
            float a2 = __builtin_amdgcn_exp2f(s00[2]);
            float a3 = __builtin_amdgcn_exp2f(s00[3]);
            float b0 = __builtin_amdgcn_exp2f(s01[0]);
            float b1 = __builtin_amdgcn_exp2f(s01[1]);
            float b2 = __builtin_amdgcn_exp2f(s01[2]);
            float b3 = __builtin_amdgcn_exp2f(s01[3]);
            float c0 = __builtin_amdgcn_exp2f(s10[0]);
            float c1 = __builtin_amdgcn_exp2f(s10[1]);
            float c2 = __builtin_amdgcn_exp2f(s10[2]);
            float c3 = __builtin_amdgcn_exp2f(s10[3]);
            float d0 = __builtin_amdgcn_exp2f(s11[0]);
            float d1 = __builtin_amdgcn_exp2f(s11[1]);
            float d2 = __builtin_amdgcn_exp2f(s11[2]);
            float d3 = __builtin_amdgcn_exp2f(s11[3]);

            uint2 u00 = make_uint2(pk_tr(a0, a1), pk_tr(a2, a3));  // m=4q+r,    nf0
            uint2 u01 = make_uint2(pk_tr(b0, b1), pk_tr(b2, b3));  // m=16+4q+r, nf0
            uint2 u10 = make_uint2(pk_tr(c0, c1), pk_tr(c2, c3));  // m=4q+r,    nf1
            uint2 u11 = make_uint2(pk_tr(d0, d1), pk_tr(d2, d3));  // m=16+4q+r, nf1
            s16x4 P00 = *(s16x4*)&u00;
            s16x4 P01 = *(s16x4*)&u01;
            s16x4 P10 = *(s16x4*)&u10;
            s16x4 P11 = *(s16x4*)&u11;

            // denominator on the MFMA pipe: accL = sum_m P (all rows identical)
            accL0 = __builtin_amdgcn_mfma_f32_16x16x16bf16_1k(ONE4, P00, accL0, 0, 0, 0);
            accL0 = __builtin_amdgcn_mfma_f32_16x16x16bf16_1k(ONE4, P01, accL0, 0, 0, 0);
            accL1 = __builtin_amdgcn_mfma_f32_16x16x16bf16_1k(ONE4, P10, accL1, 0, 0, 0);
            accL1 = __builtin_amdgcn_mfma_f32_16x16x16bf16_1k(ONE4, P11, accL1, 0, 0, 0);

            s16x4 G0a = __builtin_shufflevector(G0, G0, 0, 1, 2, 3);
            s16x4 G0b = __builtin_shufflevector(G0, G0, 4, 5, 6, 7);
            s16x4 G1a = __builtin_shufflevector(G1, G1, 0, 1, 2, 3);
            s16x4 G1b = __builtin_shufflevector(G1, G1, 4, 5, 6, 7);
            acc00 = __builtin_amdgcn_mfma_f32_16x16x16bf16_1k(G0a, P00, acc00, 0, 0, 0);
            acc00 = __builtin_amdgcn_mfma_f32_16x16x16bf16_1k(G0b, P01, acc00, 0, 0, 0);
            acc10 = __builtin_amdgcn_mfma_f32_16x16x16bf16_1k(G1a, P00, acc10, 0, 0, 0);
            acc10 = __builtin_amdgcn_mfma_f32_16x16x16bf16_1k(G1b, P01, acc10, 0, 0, 0);
            acc01 = __builtin_amdgcn_mfma_f32_16x16x16bf16_1k(G0a, P10, acc01, 0, 0, 0);
            acc01 = __builtin_amdgcn_mfma_f32_16x16x16bf16_1k(G0b, P11, acc01, 0, 0, 0);
            acc11 = __builtin_amdgcn_mfma_f32_16x16x16bf16_1k(G1a, P10, acc11, 0, 0, 0);
            acc11 = __builtin_amdgcn_mfma_f32_16x16x16bf16_1k(G1b, P11, acc11, 0, 0, 0);
        }
        __syncthreads();   // single barrier/st; drains next-st DMA (vmcnt) too
    }

    // softmax denominators: accL rows identical, col = own nl -> no shuffles
    float li0 = 1.0f / accL0[0];
    float li1 = 1.0f / accL1[0];
    acc00 *= li0; acc10 *= li0;
    acc01 *= li1; acc11 *= li1;

    // w_o A-frags: A[row=cc=16g4+nl][k=c=8q+j]
    s16x8 WO[4];
#pragma unroll
    for (int g4 = 0; g4 < 4; g4++) {
        const float4* wr = (const float4*)(w_o + (size_t)(g4 * 16 + nl) * 32 + q * 8);
        float4 a0 = wr[0], a1 = wr[1];
        WO[g4][0] = (short)f32_bf16(a0.x); WO[g4][1] = (short)f32_bf16(a0.y);
        WO[g4][2] = (short)f32_bf16(a0.z); WO[g4][3] = (short)f32_bf16(a0.w);
        WO[g4][4] = (short)f32_bf16(a1.x); WO[g4][5] = (short)f32_bf16(a1.y);
        WO[g4][6] = (short)f32_bf16(a1.z); WO[g4][7] = (short)f32_bf16(a1.w);
    }
    float gam = gamma[0];

    // O_s overlay in g-buf0 region (last compute used buf1; post-barrier safe).
    int nloc0 = w * 32 + nl;
    int nloc1 = nloc0 + 16;
    {
        uint2 ov;
        ov.x = pk_bf16(acc00[0], acc00[1]); ov.y = pk_bf16(acc00[2], acc00[3]);
        *(uint2*)(O_s + nloc0 * 80 + q * 8) = ov;           // c = 4q..4q+3
        ov.x = pk_bf16(acc10[0], acc10[1]); ov.y = pk_bf16(acc10[2], acc10[3]);
        *(uint2*)(O_s + nloc0 * 80 + 32 + q * 8) = ov;      // c = 16+4q..
        ov.x = pk_bf16(acc01[0], acc01[1]); ov.y = pk_bf16(acc01[2], acc01[3]);
        *(uint2*)(O_s + nloc1 * 80 + q * 8) = ov;
        ov.x = pk_bf16(acc11[0], acc11[1]); ov.y = pk_bf16(acc11[2], acc11[3]);
        *(uint2*)(O_s + nloc1 * 80 + 32 + q * 8) = ov;
    }
    s16x8 OB0 = *(const s16x8*)(O_s + nloc0 * 80 + q * 16);  // wave-local rows
    s16x8 OB1 = *(const s16x8*)(O_s + nloc1 * 80 + q * 16);
#pragma unroll
    for (int g4 = 0; g4 < 4; g4++) {
        f32x4 e0 = (f32x4){0.f, 0.f, 0.f, 0.f};
        f32x4 e1 = (f32x4){0.f, 0.f, 0.f, 0.f};
        e0 = __builtin_amdgcn_mfma_f32_16x16x32_bf16(WO[g4], OB0, e0, 0, 0, 0);
        e1 = __builtin_amdgcn_mfma_f32_16x16x32_bf16(WO[g4], OB1, e1, 0, 0, 0);
#pragma unroll
        for (int r = 0; r < 4; r++) {
            int cc = g4 * 16 + q * 4 + r;
            size_t gi0 = (((size_t)(b * 64 + cc)) << 14) + nw + nl;
            out[gi0] = gam * e0[r] + x[gi0];
            size_t gi1 = gi0 + 16;
            out[gi1] = gam * e1[r] + x[gi1];
        }
    }
}

extern "C" void kernel_launch(void* const* d_in, const int* in_sizes, int n_in,
                              void* d_out, int out_size, void* d_ws, size_t ws_size,
                              hipStream_t stream) {
    const float* x       = (const float*)d_in[0];
    const float* w_theta = (const float*)d_in[1];
    const float* w_phi   = (const float*)d_in[2];
    const float* w_g     = (const float*)d_in[3];
    const float* w_o     = (const float*)d_in[4];
    const float* gamma   = (const float*)d_in[5];
    float* out = (float*)d_out;

    __hip_bfloat16* thG = (__hip_bfloat16*)d_ws;        // 4*16384*8 = 1 MB
    __hip_bfloat16* phG = thG + 524288;                 // 4*4096*8  = 256 KB
    __hip_bfloat16* gG  = phG + 131072;                 // 4*32*4096 = 1 MB

    proj_kernel<<<512, 256, 0, stream>>>(x, w_theta, w_phi, w_g, thG, phG, gG);
    attn_kernel<<<512, 256, 0, stream>>>(thG, phG, gG, w_o, gamma, x, out);
}

// Round 3
// 127.532 us; speedup vs baseline: 1.0753x; 1.0753x over previous
//
#include <hip/hip_runtime.h>
#include <hip/hip_bf16.h>

// SAGAN self-attention, MI355X gfx950. B=4, C=64, H=W=128, N=16384, M=4096.
// fp32 in/out. Round 13: 32x32x16 MFMA restructure. Calibration from R11/R12
// showed ~15-16 cyc per MFMA *instruction* (latency/issue-bound at 2 waves/
// SIMD) -> minimize MFMA instr count: per 32m x 32n tile, 1 score MFMA +
// 2 PV MFMAs (was 12 16x16 MFMAs). gG's per-32-m permutation pi re-derived so
// PV B-frags are direct in-lane packs of the exp2 outputs (no cross-lane
// exchange) and each G A-frag is one b128. Denominator back on VALU as a
// v_pk_add_f32 tree (ones-MFMA denominator was the R12 regression).
// Layouts (guide-verified): 32x32x16 A[row=lane&31][k=8h+j], B[k=8h+j]
// [col=lane&31] (h=lane>>5); C/D[row=(r&3)+8(r>>2)+4h][col=lane&31].

typedef __attribute__((ext_vector_type(16))) float f32x16;
typedef __attribute__((ext_vector_type(4))) float f32x4;
typedef __attribute__((ext_vector_type(2))) float f32x2;
typedef __attribute__((ext_vector_type(8))) short s16x8;

__device__ __forceinline__ unsigned short f32_bf16(float f) {
    unsigned int u = __float_as_uint(f);
    return (unsigned short)((u + 0x7fffu + ((u >> 16) & 1u)) >> 16);  // RNE
}
__device__ __forceinline__ unsigned int pk_bf16(float a, float b) {
    return (unsigned int)f32_bf16(a) | ((unsigned int)f32_bf16(b) << 16);
}
__device__ __forceinline__ unsigned int pk_rh(float a, float b) {   // round-half-up
    unsigned int au = __float_as_uint(a) + 0x8000u;
    unsigned int bu = __float_as_uint(b) + 0x8000u;
    return __builtin_amdgcn_perm(bu, au, 0x07060302u);
}
__device__ __forceinline__ unsigned int pk_tr(float a, float b) {   // truncate
    return __builtin_amdgcn_perm(__float_as_uint(b), __float_as_uint(a), 0x07060302u);
}
// async 16B/lane global->LDS DMA; lds dest = wave-uniform base + lane*16
__device__ __forceinline__ void async16(const void* g, void* l) {
    __builtin_amdgcn_global_load_lds(
        (const __attribute__((address_space(1))) unsigned int*)g,
        (__attribute__((address_space(3))) unsigned int*)l, 16, 0, 0);
}

// ---------------- proj: theta/phi/g 1x1 conv + 2x2 maxpool, MFMA ----------------
// (round 10 verbatim EXCEPT the gG permutation pi, re-derived for the 32x32 PV:
//  storage index i(mm) = 16*a + 8*c + 4*b + d for mm = 16a+8b+4c+d, so that
//  16B slot s=2pv+h holds m = 16pv + 4h + 8*(j>>2) + (j&3) in j-order.)
__global__ __launch_bounds__(256) void proj_kernel(
    const float* __restrict__ x,
    const float* __restrict__ w_theta, const float* __restrict__ w_phi,
    const float* __restrict__ w_g,
    __hip_bfloat16* __restrict__ thG,   // [b][n][8]  (theta * log2e)
    __hip_bfloat16* __restrict__ phG,   // [b][m][8]
    __hip_bfloat16* __restrict__ gG)    // [b][32][4096], pi-permuted per 32-m chunk
{
    __shared__ __align__(16) unsigned short x_s[128 * 72];  // [pix][c], 144 B rows
    int tid = threadIdx.x;
    int bx = blockIdx.x;
    int b = bx >> 7, mh = (bx >> 1) & 63, ph = bx & 1;

    {   // phase 1: float4 loads (c-pair per thread), packed u32 LDS transpose
        int cp = tid >> 3, s = tid & 7;
        const float* xb = x + ((size_t)b << 20) + (size_t)(2 * mh) * 128 + 64 * ph;
        const float* p0r = xb + ((size_t)(2 * cp) << 14);
        const float* p1r = p0r + (1 << 14);
#pragma unroll
        for (int py = 0; py < 2; py++)
#pragma unroll
            for (int t = 0; t < 2; t++) {
                int pxl = 4 * s + 32 * t;
                float4 a = *(const float4*)(p0r + py * 128 + pxl);
                float4 c = *(const float4*)(p1r + py * 128 + pxl);
                int pix = py * 64 + pxl;
                *(unsigned int*)&x_s[(pix + 0) * 72 + 2 * cp] = pk_rh(a.x, c.x);
                *(unsigned int*)&x_s[(pix + 1) * 72 + 2 * cp] = pk_rh(a.y, c.y);
                *(unsigned int*)&x_s[(pix + 2) * 72 + 2 * cp] = pk_rh(a.z, c.z);
                *(unsigned int*)&x_s[(pix + 3) * 72 + 2 * cp] = pk_rh(a.w, c.w);
            }
    }

    int lane = tid & 63, w = tid >> 6;
    int q = lane >> 4, nl = lane & 15;

    s16x8 A[3][2];
#pragma unroll
    for (int CT = 0; CT < 3; CT++) {
        const float* wsrc;
        float scale = 1.0f;
        if (CT == 0) {
            if (nl < 8) { wsrc = w_theta + nl * 64; scale = 1.44269504f; }
            else        { wsrc = w_phi + (nl - 8) * 64; }
        } else if (CT == 1) wsrc = w_g + nl * 64;
        else                wsrc = w_g + (16 + nl) * 64;
#pragma unroll
        for (int ks = 0; ks < 2; ks++) {
            const float4* p4 = (const float4*)(wsrc + 32 * ks + 8 * q);
            float4 a0 = p4[0], a1 = p4[1];
            s16x8 f;
            f[0] = (short)f32_bf16(a0.x * scale); f[1] = (short)f32_bf16(a0.y * scale);
            f[2] = (short)f32_bf16(a0.z * scale); f[3] = (short)f32_bf16(a0.w * scale);
            f[4] = (short)f32_bf16(a1.x * scale); f[5] = (short)f32_bf16(a1.y * scale);
            f[6] = (short)f32_bf16(a1.z * scale); f[7] = (short)f32_bf16(a1.w * scale);
            A[CT][ks] = f;
        }
    }
    __syncthreads();

    f32x4 acc[3][2];
#pragma unroll
    for (int ti = 0; ti < 2; ti++) {
        int tile = w + 4 * ti;
        const unsigned short* rb = x_s + (16 * tile + nl) * 72;
        s16x8 B0 = *(const s16x8*)(rb + 8 * q);
        s16x8 B1 = *(const s16x8*)(rb + 32 + 8 * q);
#pragma unroll
        for (int CT = 0; CT < 3; CT++) {
            f32x4 d = (f32x4){0.f, 0.f, 0.f, 0.f};
            d = __builtin_amdgcn_mfma_f32_16x16x32_bf16(A[CT][0], B0, d, 0, 0, 0);
            d = __builtin_amdgcn_mfma_f32_16x16x32_bf16(A[CT][1], B1, d, 0, 0, 0);
            acc[CT][ti] = d;
        }
    }

    if (q < 2) {
        unsigned short* thb = (unsigned short*)thG + ((size_t)b << 14) * 8;
#pragma unroll
        for (int ti = 0; ti < 2; ti++) {
            int n = (2 * mh + ti) * 128 + 64 * ph + 16 * w + nl;
            uint2 tv;
            tv.x = pk_bf16(acc[0][ti][0], acc[0][ti][1]);
            tv.y = pk_bf16(acc[0][ti][2], acc[0][ti][3]);
            *(uint2*)(thb + (size_t)n * 8 + 4 * q) = tv;
        }
    }

    float pool[3][4];
#pragma unroll
    for (int CT = 0; CT < 3; CT++)
#pragma unroll
        for (int r = 0; r < 4; r++) {
            float a = fmaxf(acc[CT][0][r], acc[CT][1][r]);
            pool[CT][r] = fmaxf(a, __shfl_xor(a, 1));
        }

    int mm = 8 * w + (nl >> 1);
    int mbase = mh * 64 + ph * 32;
    if ((nl & 1) == 0) {
        if (q >= 2) {
            uint2 pv;
            pv.x = pk_bf16(pool[0][0], pool[0][1]);
            pv.y = pk_bf16(pool[0][2], pool[0][3]);
            *(uint2*)((unsigned short*)phG + ((size_t)(b * 4096 + mbase + mm)) * 8 + (q - 2) * 4) = pv;
        }
        // pi for 32x32 PV A-frags: i = 16*((mm>>4)&1) + 8*((mm>>2)&1) + 4*((mm>>3)&1) + (mm&3)
        int p = 16 * ((mm >> 4) & 1) + 8 * ((mm >> 2) & 1) + 4 * ((mm >> 3) & 1) + (mm & 3);
        int mstore = mbase + p;
#pragma unroll
        for (int CT = 1; CT < 3; CT++)
#pragma unroll
            for (int r = 0; r < 4; r++) {
                int cg = 16 * (CT - 1) + 4 * q + r;
                ((unsigned short*)gG)[((size_t)(b * 32 + cg) << 12) + mstore] =
                    f32_bf16(pool[CT][r]);
            }
    }
}

// ---------------- attn: 32x32x16 score -> exp2 -> 2x 32x32x16 PV ----------------
// Grid 512 = b(4) x n-tile(128). Block 256 thr = 4 waves x 32 n, full m.
// LDS: g dbuf 2x16384 (rows 512B, XOR-swizzled 16B slots) + phi dbuf 2x4096.
__global__ __launch_bounds__(256) void attn_kernel(
    const __hip_bfloat16* __restrict__ thG, const __hip_bfloat16* __restrict__ phG,
    const __hip_bfloat16* __restrict__ gG,
    const float* __restrict__ w_o, const float* __restrict__ gamma,
    const float* __restrict__ x, float* __restrict__ out)
{
    __shared__ __align__(16) unsigned char smem[2 * 16384 + 2 * 4096];  // 40960 B
    unsigned char* O_s = smem;   // epilogue overlay [128][80 B] (g buf0 region)

    int tid = threadIdx.x, lane = tid & 63, w = tid >> 6;   // w: 0..3
    int q = lane >> 4, nl = lane & 15;
    int c31 = lane & 31, h = lane >> 5;
    int bx = blockIdx.x;
    int b  = bx >> 7;
    int n0 = (bx & 127) << 7;
    int nw = n0 + w * 32;

    const unsigned short* thb = (const unsigned short*)thG + ((size_t)b << 14) * 8;
    const unsigned short* phb = (const unsigned short*)phG + ((size_t)b << 12) * 8;
    const unsigned short* ggb = (const unsigned short*)gG + ((size_t)b << 17);

    // theta B-frag (32x32x16): B[k=c=8h+j][col=n=c31]; h=1/j=0 = bias slot
    s16x8 BT = (s16x8){0, 0, 0, 0, 0, 0, 0, 0};
    if (h == 0) BT = *(const s16x8*)(thb + (size_t)(nw + c31) * 8);
    else        BT[0] = (short)0xC167;   // bf16(-14.4375)
    // phi A-frag const part: h=1/j=0 -> k=8 slot = 1.0
    s16x8 Fc = (s16x8){0, 0, 0, 0, 0, 0, 0, 0};
    if (h == 1) Fc[0] = (short)0x3F80;

    f32x16 acc = {};          // PV acc: [row=c=(r&3)+8(r>>2)+4h][col=n=c31]
    f32x2  l2 = (f32x2){0.f, 0.f};

    // async staging: wave w stages g rows 8w..8w+7 (4 calls, 2 rows each);
    // lane i -> LDS slot i&31 of row (i>>5); source slot = (i&31) XOR row.
    int r0 = 8 * w + (lane >> 5);
    const unsigned short* gsrc0 = ggb + ((size_t)(r0 + 0) << 12) + 8 * ((lane & 31) ^ (r0 + 0));
    const unsigned short* gsrc1 = ggb + ((size_t)(r0 + 2) << 12) + 8 * ((lane & 31) ^ (r0 + 2));
    const unsigned short* gsrc2 = ggb + ((size_t)(r0 + 4) << 12) + 8 * ((lane & 31) ^ (r0 + 4));
    const unsigned short* gsrc3 = ggb + ((size_t)(r0 + 6) << 12) + 8 * ((lane & 31) ^ (r0 + 6));
    const unsigned short* psrc  = phb + (size_t)(w * 64 + lane) * 8;
    unsigned char* ldsg0 = smem + w * 4096;            // + buf*16384
    unsigned char* ldsg1 = ldsg0 + 1024;
    unsigned char* ldsg2 = ldsg0 + 2048;
    unsigned char* ldsg3 = ldsg0 + 3072;
    unsigned char* ldsp  = smem + 32768 + w * 1024;    // + buf*4096

    // pre-stage st 0 -> buf 0
    async16(gsrc0, ldsg0);
    async16(gsrc1, ldsg1);
    async16(gsrc2, ldsg2);
    async16(gsrc3, ldsg3);
    async16(psrc, ldsp);
    __syncthreads();

    for (int st = 0; st < 16; st++) {
        const unsigned char* gcur = smem + (st & 1) * 16384;
        const unsigned char* pcur = smem + 32768 + (st & 1) * 4096;
        if (st < 15) {   // issue next st's DMA into the other buffers (no wait)
            int mo = (st + 1) << 8;           // g element offset (256/st)
            int nb = (st + 1) & 1;
            async16(gsrc0 + mo, ldsg0 + nb * 16384);
            async16(gsrc1 + mo, ldsg1 + nb * 16384);
            async16(gsrc2 + mo, ldsg2 + nb * 16384);
            async16(gsrc3 + mo, ldsg3 + nb * 16384);
            async16(psrc + (size_t)mo * 8, ldsp + nb * 4096);
        }
#pragma unroll
        for (int t8 = 0; t8 < 8; t8++) {
            int mloc = t8 << 5;
            // phi A-frag: rows mloc..mloc+31, 16B each (contiguous, conflict-free)
            s16x8 F = Fc;
            if (h == 0) F = *(const s16x8*)(pcur + (mloc + c31) * 16);
            // G A-frags: slot s = 4*t8 + 2*pv + h, XOR-swizzled by row c
            int s0 = (t8 << 2) + h;
            s16x8 G1 = *(const s16x8*)(gcur + c31 * 512 + (((s0 + 0) ^ c31) << 4));
            s16x8 G2 = *(const s16x8*)(gcur + c31 * 512 + (((s0 + 2) ^ c31) << 4));

            f32x16 z = {};
            f32x16 S = __builtin_amdgcn_mfma_f32_32x32x16_bf16(F, BT, z, 0, 0, 0);

            float p0  = __builtin_amdgcn_exp2f(S[0]);
            float p1  = __builtin_amdgcn_exp2f(S[1]);
            float p2  = __builtin_amdgcn_exp2f(S[2]);
            float p3  = __builtin_amdgcn_exp2f(S[3]);
            float p4  = __builtin_amdgcn_exp2f(S[4]);
            float p5  = __builtin_amdgcn_exp2f(S[5]);
            float p6  = __builtin_amdgcn_exp2f(S[6]);
            float p7  = __builtin_amdgcn_exp2f(S[7]);
            float p8  = __builtin_amdgcn_exp2f(S[8]);
            float p9  = __builtin_amdgcn_exp2f(S[9]);
            float p10 = __builtin_amdgcn_exp2f(S[10]);
            float p11 = __builtin_amdgcn_exp2f(S[11]);
            float p12 = __builtin_amdgcn_exp2f(S[12]);
            float p13 = __builtin_amdgcn_exp2f(S[13]);
            float p14 = __builtin_amdgcn_exp2f(S[14]);
            float p15 = __builtin_amdgcn_exp2f(S[15]);

            // denominator on VALU: packed-f32 add tree (7 pk-adds)
            f32x2 u0 = (f32x2){p0, p1} + (f32x2){p2, p3};
            f32x2 u1 = (f32x2){p4, p5} + (f32x2){p6, p7};
            f32x2 u2 = (f32x2){p8, p9} + (f32x2){p10, p11};
            f32x2 u3 = (f32x2){p12, p13} + (f32x2){p14, p15};
            l2 += (u0 + u1) + (u2 + u3);

            // B-frags: direct in-lane packs (pi makes k-order = reg-order)
            uint4 ub1 = make_uint4(pk_tr(p0, p1), pk_tr(p2, p3),
                                   pk_tr(p4, p5), pk_tr(p6, p7));
            uint4 ub2 = make_uint4(pk_tr(p8, p9), pk_tr(p10, p11),
                                   pk_tr(p12, p13), pk_tr(p14, p15));
            s16x8 B1 = *(s16x8*)&ub1;
            s16x8 B2 = *(s16x8*)&ub2;

            acc = __builtin_amdgcn_mfma_f32_32x32x16_bf16(G1, B1, acc, 0, 0, 0);
            acc = __builtin_amdgcn_mfma_f32_32x32x16_bf16(G2, B2, acc, 0, 0, 0);
        }
        __syncthreads();   // single barrier/st; drains next-st DMA (vmcnt) too
    }

    // softmax denominator: combine halves (h=0 has m%8<4, h=1 the rest)
    float l = l2[0] + l2[1];
    l += __shfl_xor(l, 32);
    float linv = 1.0f / l;
    acc *= linv;

    // w_o A-frags: A[row=cc=16g4+nl][k=c=8q+j]
    s16x8 WO[4];
#pragma unroll
    for (int g4 = 0; g4 < 4; g4++) {
        const float4* wr = (const float4*)(w_o + (size_t)(g4 * 16 + nl) * 32 + q * 8);
        float4 a0 = wr[0], a1 = wr[1];
        WO[g4][0] = (short)f32_bf16(a0.x); WO[g4][1] = (short)f32_bf16(a0.y);
        WO[g4][2] = (short)f32_bf16(a0.z); WO[g4][3] = (short)f32_bf16(a0.w);
        WO[g4][4] = (short)f32_bf16(a1.x); WO[g4][5] = (short)f32_bf16(a1.y);
        WO[g4][6] = (short)f32_bf16(a1.z); WO[g4][7] = (short)f32_bf16(a1.w);
    }
    float gam = gamma[0];

    // O_s overlay in g-buf0 region (last compute used buf1; post-barrier safe).
    // acc reg r -> c = (r&3) + 8*(r>>2) + 4h: group g2 covers c=8*g2+4h..+3.
    int nloc = w * 32 + c31;
    {
#pragma unroll
        for (int g2 = 0; g2 < 4; g2++) {
            uint2 ov;
            ov.x = pk_bf16(acc[4 * g2 + 0], acc[4 * g2 + 1]);
            ov.y = pk_bf16(acc[4 * g2 + 2], acc[4 * g2 + 3]);
            *(uint2*)(O_s + nloc * 80 + 16 * g2 + 8 * h) = ov;
        }
    }
    int nloc0 = w * 32 + nl;
    int nloc1 = nloc0 + 16;
    s16x8 OB0 = *(const s16x8*)(O_s + nloc0 * 80 + q * 16);  // wave-local rows
    s16x8 OB1 = *(const s16x8*)(O_s + nloc1 * 80 + q * 16);
#pragma unroll
    for (int g4 = 0; g4 < 4; g4++) {
        f32x4 e0 = (f32x4){0.f, 0.f, 0.f, 0.f};
        f32x4 e1 = (f32x4){0.f, 0.f, 0.f, 0.f};
        e0 = __builtin_amdgcn_mfma_f32_16x16x32_bf16(WO[g4], OB0, e0, 0, 0, 0);
        e1 = __builtin_amdgcn_mfma_f32_16x16x32_bf16(WO[g4], OB1, e1, 0, 0, 0);
#pragma unroll
        for (int r = 0; r < 4; r++) {
            int cc = g4 * 16 + q * 4 + r;
            size_t gi0 = (((size_t)(b * 64 + cc)) << 14) + nw + nl;
            out[gi0] = gam * e0[r] + x[gi0];
            size_t gi1 = gi0 + 16;
            out[gi1] = gam * e1[r] + x[gi1];
        }
    }
}

extern "C" void kernel_launch(void* const* d_in, const int* in_sizes, int n_in,
                              void* d_out, int out_size, void* d_ws, size_t ws_size,
                              hipStream_t stream) {
    const float* x       = (const float*)d_in[0];
    const float* w_theta = (const float*)d_in[1];
    const float* w_phi   = (const float*)d_in[2];
    const float* w_g     = (const float*)d_in[3];
    const float* w_o     = (const float*)d_in[4];
    const float* gamma   = (const float*)d_in[5];
    float* out = (float*)d_out;

    __hip_bfloat16* thG = (__hip_bfloat16*)d_ws;        // 4*16384*8 = 1 MB
    __hip_bfloat16* phG = thG + 524288;                 // 4*4096*8  = 256 KB
    __hip_bfloat16* gG  = phG + 131072;                 // 4*32*4096 = 1 MB

    proj_kernel<<<512, 256, 0, stream>>>(x, w_theta, w_phi, w_g, thG, phG, gG);
    attn_kernel<<<512, 256, 0, stream>>>(thG, phG, gG, w_o, gamma, x, out);
}

// Round 4
// 117.410 us; speedup vs baseline: 1.1680x; 1.0862x over previous
//
#include <hip/hip_runtime.h>
#include <hip/hip_bf16.h>

// SAGAN self-attention, MI355X gfx950. B=4, C=64, H=W=128, N=16384, M=4096.
// fp32 in/out. Round 14: in-block m-split for occupancy. R13 showed VALU-busy
// time pinned at ~34 µs with VALUBusy 60% / occupancy 16% (2 waves/SIMD) —
// issue-gap bound. Wave-count invariant (2048 waves at 32n/wave, full m)
// broken by splitting m inside the block: 8 waves = 2 m-halves x 4 n-subtiles,
// each half runs 16 sts of 128 m-cols (half-size staging, same 40960 B LDS,
// same barrier count). Half 1 dumps partial acc+l to LDS post-loop; half 0
// combines + epilogue. 4 waves/SIMD. Inner-tile structure = R13 verbatim
// (1 score MFMA + 2 PV MFMA per 32m x 32n tile, pi-permuted gG, VALU pk-add
// denominator). Layouts: 32x32x16 A[row=lane&31][k=8h+j], B[k=8h+j]
// [col=lane&31] (h=lane>>5); C/D[row=(r&3)+8(r>>2)+4h][col=lane&31].

typedef __attribute__((ext_vector_type(16))) float f32x16;
typedef __attribute__((ext_vector_type(4))) float f32x4;
typedef __attribute__((ext_vector_type(2))) float f32x2;
typedef __attribute__((ext_vector_type(8))) short s16x8;

__device__ __forceinline__ unsigned short f32_bf16(float f) {
    unsigned int u = __float_as_uint(f);
    return (unsigned short)((u + 0x7fffu + ((u >> 16) & 1u)) >> 16);  // RNE
}
__device__ __forceinline__ unsigned int pk_bf16(float a, float b) {
    return (unsigned int)f32_bf16(a) | ((unsigned int)f32_bf16(b) << 16);
}
__device__ __forceinline__ unsigned int pk_rh(float a, float b) {   // round-half-up
    unsigned int au = __float_as_uint(a) + 0x8000u;
    unsigned int bu = __float_as_uint(b) + 0x8000u;
    return __builtin_amdgcn_perm(bu, au, 0x07060302u);
}
__device__ __forceinline__ unsigned int pk_tr(float a, float b) {   // truncate
    return __builtin_amdgcn_perm(__float_as_uint(b), __float_as_uint(a), 0x07060302u);
}
// async 16B/lane global->LDS DMA; lds dest = wave-uniform base + lane*16
__device__ __forceinline__ void async16(const void* g, void* l) {
    __builtin_amdgcn_global_load_lds(
        (const __attribute__((address_space(1))) unsigned int*)g,
        (__attribute__((address_space(3))) unsigned int*)l, 16, 0, 0);
}

// ---------------- proj: theta/phi/g 1x1 conv + 2x2 maxpool, MFMA ----------------
// (round 13 verbatim — passed; emits pi-permuted gG for the 32x32 PV)
__global__ __launch_bounds__(256) void proj_kernel(
    const float* __restrict__ x,
    const float* __restrict__ w_theta, const float* __restrict__ w_phi,
    const float* __restrict__ w_g,
    __hip_bfloat16* __restrict__ thG,   // [b][n][8]  (theta * log2e)
    __hip_bfloat16* __restrict__ phG,   // [b][m][8]
    __hip_bfloat16* __restrict__ gG)    // [b][32][4096], pi-permuted per 32-m chunk
{
    __shared__ __align__(16) unsigned short x_s[128 * 72];  // [pix][c], 144 B rows
    int tid = threadIdx.x;
    int bx = blockIdx.x;
    int b = bx >> 7, mh = (bx >> 1) & 63, ph = bx & 1;

    {   // phase 1: float4 loads (c-pair per thread), packed u32 LDS transpose
        int cp = tid >> 3, s = tid & 7;
        const float* xb = x + ((size_t)b << 20) + (size_t)(2 * mh) * 128 + 64 * ph;
        const float* p0r = xb + ((size_t)(2 * cp) << 14);
        const float* p1r = p0r + (1 << 14);
#pragma unroll
        for (int py = 0; py < 2; py++)
#pragma unroll
            for (int t = 0; t < 2; t++) {
                int pxl = 4 * s + 32 * t;
                float4 a = *(const float4*)(p0r + py * 128 + pxl);
                float4 c = *(const float4*)(p1r + py * 128 + pxl);
                int pix = py * 64 + pxl;
                *(unsigned int*)&x_s[(pix + 0) * 72 + 2 * cp] = pk_rh(a.x, c.x);
                *(unsigned int*)&x_s[(pix + 1) * 72 + 2 * cp] = pk_rh(a.y, c.y);
                *(unsigned int*)&x_s[(pix + 2) * 72 + 2 * cp] = pk_rh(a.z, c.z);
                *(unsigned int*)&x_s[(pix + 3) * 72 + 2 * cp] = pk_rh(a.w, c.w);
            }
    }

    int lane = tid & 63, w = tid >> 6;
    int q = lane >> 4, nl = lane & 15;

    s16x8 A[3][2];
#pragma unroll
    for (int CT = 0; CT < 3; CT++) {
        const float* wsrc;
        float scale = 1.0f;
        if (CT == 0) {
            if (nl < 8) { wsrc = w_theta + nl * 64; scale = 1.44269504f; }
            else        { wsrc = w_phi + (nl - 8) * 64; }
        } else if (CT == 1) wsrc = w_g + nl * 64;
        else                wsrc = w_g + (16 + nl) * 64;
#pragma unroll
        for (int ks = 0; ks < 2; ks++) {
            const float4* p4 = (const float4*)(wsrc + 32 * ks + 8 * q);
            float4 a0 = p4[0], a1 = p4[1];
            s16x8 f;
            f[0] = (short)f32_bf16(a0.x * scale); f[1] = (short)f32_bf16(a0.y * scale);
            f[2] = (short)f32_bf16(a0.z * scale); f[3] = (short)f32_bf16(a0.w * scale);
            f[4] = (short)f32_bf16(a1.x * scale); f[5] = (short)f32_bf16(a1.y * scale);
            f[6] = (short)f32_bf16(a1.z * scale); f[7] = (short)f32_bf16(a1.w * scale);
            A[CT][ks] = f;
        }
    }
    __syncthreads();

    f32x4 acc[3][2];
#pragma unroll
    for (int ti = 0; ti < 2; ti++) {
        int tile = w + 4 * ti;
        const unsigned short* rb = x_s + (16 * tile + nl) * 72;
        s16x8 B0 = *(const s16x8*)(rb + 8 * q);
        s16x8 B1 = *(const s16x8*)(rb + 32 + 8 * q);
#pragma unroll
        for (int CT = 0; CT < 3; CT++) {
            f32x4 d = (f32x4){0.f, 0.f, 0.f, 0.f};
            d = __builtin_amdgcn_mfma_f32_16x16x32_bf16(A[CT][0], B0, d, 0, 0, 0);
            d = __builtin_amdgcn_mfma_f32_16x16x32_bf16(A[CT][1], B1, d, 0, 0, 0);
            acc[CT][ti] = d;
        }
    }

    if (q < 2) {
        unsigned short* thb = (unsigned short*)thG + ((size_t)b << 14) * 8;
#pragma unroll
        for (int ti = 0; ti < 2; ti++) {
            int n = (2 * mh + ti) * 128 + 64 * ph + 16 * w + nl;
            uint2 tv;
            tv.x = pk_bf16(acc[0][ti][0], acc[0][ti][1]);
            tv.y = pk_bf16(acc[0][ti][2], acc[0][ti][3]);
            *(uint2*)(thb + (size_t)n * 8 + 4 * q) = tv;
        }
    }

    float pool[3][4];
#pragma unroll
    for (int CT = 0; CT < 3; CT++)
#pragma unroll
        for (int r = 0; r < 4; r++) {
            float a = fmaxf(acc[CT][0][r], acc[CT][1][r]);
            pool[CT][r] = fmaxf(a, __shfl_xor(a, 1));
        }

    int mm = 8 * w + (nl >> 1);
    int mbase = mh * 64 + ph * 32;
    if ((nl & 1) == 0) {
        if (q >= 2) {
            uint2 pv;
            pv.x = pk_bf16(pool[0][0], pool[0][1]);
            pv.y = pk_bf16(pool[0][2], pool[0][3]);
            *(uint2*)((unsigned short*)phG + ((size_t)(b * 4096 + mbase + mm)) * 8 + (q - 2) * 4) = pv;
        }
        // pi for 32x32 PV A-frags: i = 16*((mm>>4)&1) + 8*((mm>>2)&1) + 4*((mm>>3)&1) + (mm&3)
        int p = 16 * ((mm >> 4) & 1) + 8 * ((mm >> 2) & 1) + 4 * ((mm >> 3) & 1) + (mm & 3);
        int mstore = mbase + p;
#pragma unroll
        for (int CT = 1; CT < 3; CT++)
#pragma unroll
            for (int r = 0; r < 4; r++) {
                int cg = 16 * (CT - 1) + 4 * q + r;
                ((unsigned short*)gG)[((size_t)(b * 32 + cg) << 12) + mstore] =
                    f32_bf16(pool[CT][r]);
            }
    }
}

// ---------------- attn: m-split 8-wave, 32x32x16 score -> exp2 -> 2x PV --------
// Grid 512 = b(4) x n-tile(128). Block 512 thr = 2 m-halves x 4 waves x 32 n.
// Each half: 16 sts x 128 m-cols. LDS per half: g dbuf 2x8192 + phi dbuf 2x2048.
// Map: gA[0,16384) gB[16384,32768) pA[32768,36864) pB[36864,40960).
__global__ __launch_bounds__(512, 4) void attn_kernel(
    const __hip_bfloat16* __restrict__ thG, const __hip_bfloat16* __restrict__ phG,
    const __hip_bfloat16* __restrict__ gG,
    const float* __restrict__ w_o, const float* __restrict__ gamma,
    const float* __restrict__ x, float* __restrict__ out)
{
    __shared__ __align__(64) unsigned char smem[40960];

    int tid = threadIdx.x, lane = tid & 63, w = tid >> 6;   // w: 0..7
    int w4 = w & 3, hf = w >> 2;
    int q = lane >> 4, nl = lane & 15;
    int c31 = lane & 31, h = lane >> 5;
    int bx = blockIdx.x;
    int b  = bx >> 7;
    int n0 = (bx & 127) << 7;
    int nw = n0 + w4 * 32;

    const unsigned short* thb = (const unsigned short*)thG + ((size_t)b << 14) * 8;
    const unsigned short* phb = (const unsigned short*)phG + ((size_t)b << 12) * 8;
    const unsigned short* ggb = (const unsigned short*)gG + ((size_t)b << 17);

    // theta B-frag (32x32x16): B[k=c=8h+j][col=n=c31]; h=1/j=0 = bias slot
    s16x8 BT = (s16x8){0, 0, 0, 0, 0, 0, 0, 0};
    if (h == 0) BT = *(const s16x8*)(thb + (size_t)(nw + c31) * 8);
    else        BT[0] = (short)0xC167;   // bf16(-14.4375)
    // phi A-frag const part: h=1/j=0 -> k=8 slot = 1.0
    s16x8 Fc = (s16x8){0, 0, 0, 0, 0, 0, 0, 0};
    if (h == 1) Fc[0] = (short)0x3F80;

    f32x16 acc = {};          // PV acc: [row=c=(r&3)+8(r>>2)+4h][col=n=c31]
    f32x2  l2 = (f32x2){0.f, 0.f};

    // staging: per wave 2 g-calls (rows 8w4..+3, 8w4+4..+7 of this half's st) +
    // phi (waves w4<2). LDS slot s of row r holds logical slot s^(r&15).
    int rA = 8 * w4 + (lane >> 4);       // k=0 rows
    int rB = rA + 4;                     // k=1 rows
    const unsigned short* gsrcA = ggb + ((size_t)rA << 12) + (hf << 11)
                                  + (((lane & 15) ^ (rA & 15)) << 3);
    const unsigned short* gsrcB = ggb + ((size_t)rB << 12) + (hf << 11)
                                  + (((lane & 15) ^ (rB & 15)) << 3);
    const unsigned short* psrc  = phb + (size_t)((hf << 11) + w4 * 64 + lane) * 8;
    unsigned char* gdst = smem + hf * 16384 + w4 * 2048;        // + k*1024 + buf*8192
    unsigned char* pdst = smem + 32768 + hf * 4096 + w4 * 1024; // + buf*2048 (w4<2)

    // pre-stage st 0 -> buf 0
    async16(gsrcA, gdst);
    async16(gsrcB, gdst + 1024);
    if (w4 < 2) async16(psrc, pdst);
    __syncthreads();

    for (int st = 0; st < 16; st++) {
        const unsigned char* gcur = smem + hf * 16384 + (st & 1) * 8192;
        const unsigned char* pcur = smem + 32768 + hf * 4096 + (st & 1) * 2048;
        if (st < 15) {   // issue next st's DMA into the other buffers (no wait)
            int nb = (st + 1) & 1;
            int mo = (st + 1) << 7;           // g element offset (128/st)
            async16(gsrcA + mo, gdst + nb * 8192);
            async16(gsrcB + mo, gdst + nb * 8192 + 1024);
            if (w4 < 2) async16(psrc + (size_t)mo * 8, pdst + nb * 2048);
        }
#pragma unroll
        for (int t8 = 0; t8 < 4; t8++) {
            int mloc = t8 << 5;
            // phi A-frag: rows mloc..mloc+31 of this st (contiguous 16B)
            s16x8 F = Fc;
            if (h == 0) F = *(const s16x8*)(pcur + (mloc + c31) * 16);
            // G A-frags: logical slot 4*t8+2*pv+h, LDS slot = logical^(c31&15)
            int s0 = (t8 << 2) + h;
            int m15 = c31 & 15;
            s16x8 G1 = *(const s16x8*)(gcur + c31 * 256 + (((s0 + 0) ^ m15) << 4));
            s16x8 G2 = *(const s16x8*)(gcur + c31 * 256 + (((s0 + 2) ^ m15) << 4));

            f32x16 z = {};
            f32x16 S = __builtin_amdgcn_mfma_f32_32x32x16_bf16(F, BT, z, 0, 0, 0);

            float p0  = __builtin_amdgcn_exp2f(S[0]);
            float p1  = __builtin_amdgcn_exp2f(S[1]);
            float p2  = __builtin_amdgcn_exp2f(S[2]);
            float p3  = __builtin_amdgcn_exp2f(S[3]);
            float p4  = __builtin_amdgcn_exp2f(S[4]);
            float p5  = __builtin_amdgcn_exp2f(S[5]);
            float p6  = __builtin_amdgcn_exp2f(S[6]);
            float p7  = __builtin_amdgcn_exp2f(S[7]);
            float p8  = __builtin_amdgcn_exp2f(S[8]);
            float p9  = __builtin_amdgcn_exp2f(S[9]);
            float p10 = __builtin_amdgcn_exp2f(S[10]);
            float p11 = __builtin_amdgcn_exp2f(S[11]);
            float p12 = __builtin_amdgcn_exp2f(S[12]);
            float p13 = __builtin_amdgcn_exp2f(S[13]);
            float p14 = __builtin_amdgcn_exp2f(S[14]);
            float p15 = __builtin_amdgcn_exp2f(S[15]);

            // denominator on VALU: packed-f32 add tree (7 pk-adds)
            f32x2 u0 = (f32x2){p0, p1} + (f32x2){p2, p3};
            f32x2 u1 = (f32x2){p4, p5} + (f32x2){p6, p7};
            f32x2 u2 = (f32x2){p8, p9} + (f32x2){p10, p11};
            f32x2 u3 = (f32x2){p12, p13} + (f32x2){p14, p15};
            l2 += (u0 + u1) + (u2 + u3);

            // B-frags: direct in-lane packs (pi makes k-order = reg-order)
            uint4 ub1 = make_uint4(pk_tr(p0, p1), pk_tr(p2, p3),
                                   pk_tr(p4, p5), pk_tr(p6, p7));
            uint4 ub2 = make_uint4(pk_tr(p8, p9), pk_tr(p10, p11),
                                   pk_tr(p12, p13), pk_tr(p14, p15));
            s16x8 B1 = *(s16x8*)&ub1;
            s16x8 B2 = *(s16x8*)&ub2;

            acc = __builtin_amdgcn_mfma_f32_32x32x16_bf16(G1, B1, acc, 0, 0, 0);
            acc = __builtin_amdgcn_mfma_f32_32x32x16_bf16(G2, B2, acc, 0, 0, 0);
        }
        __syncthreads();   // single barrier/st; drains next-st DMA (vmcnt) too
    }

    // per-half denominator: combine h-halves (h=0: m%8<4, h=1: rest)
    float l = l2[0] + l2[1];
    l += __shfl_xor(l, 32);

    // cross-half combine: half 1 dumps partials into now-free staging LDS
    int idx = (w4 << 6) + lane;          // 0..255, lane-aligned across halves
    if (hf == 1) {
        *(f32x16*)(smem + idx * 64) = acc;                 // [0,16384)
        *(float*)(smem + 32768 + idx * 4) = l;             // pA buf0, 1 KB
    }
    __syncthreads();
    if (hf == 0) {
        f32x16 accB = *(const f32x16*)(smem + idx * 64);
        float lB = *(const float*)(smem + 32768 + idx * 4);
        acc += accB;
        float linv = 1.0f / (l + lB);
        acc *= linv;

        // w_o A-frags: A[row=cc=16g4+nl][k=c=8q+j]
        s16x8 WO[4];
#pragma unroll
        for (int g4 = 0; g4 < 4; g4++) {
            const float4* wr = (const float4*)(w_o + (size_t)(g4 * 16 + nl) * 32 + q * 8);
            float4 a0 = wr[0], a1 = wr[1];
            WO[g4][0] = (short)f32_bf16(a0.x); WO[g4][1] = (short)f32_bf16(a0.y);
            WO[g4][2] = (short)f32_bf16(a0.z); WO[g4][3] = (short)f32_bf16(a0.w);
            WO[g4][4] = (short)f32_bf16(a1.x); WO[g4][5] = (short)f32_bf16(a1.y);
            WO[g4][6] = (short)f32_bf16(a1.z); WO[g4][7] = (short)f32_bf16(a1.w);
        }
        float gam = gamma[0];

        // O_s overlay [128][80 B] at 20480 (free; no overlap with dump/l regions)
        unsigned char* O_s = smem + 20480;
        int nloc = w4 * 32 + c31;
#pragma unroll
        for (int g2 = 0; g2 < 4; g2++) {
            uint2 ov;
            ov.x = pk_bf16(acc[4 * g2 + 0], acc[4 * g2 + 1]);
            ov.y = pk_bf16(acc[4 * g2 + 2], acc[4 * g2 + 3]);
            *(uint2*)(O_s + nloc * 80 + 16 * g2 + 8 * h) = ov;
        }
        int nloc0 = w4 * 32 + nl;
        int nloc1 = nloc0 + 16;
        s16x8 OB0 = *(const s16x8*)(O_s + nloc0 * 80 + q * 16);  // wave-local rows
        s16x8 OB1 = *(const s16x8*)(O_s + nloc1 * 80 + q * 16);
#pragma unroll
        for (int g4 = 0; g4 < 4; g4++) {
            f32x4 e0 = (f32x4){0.f, 0.f, 0.f, 0.f};
            f32x4 e1 = (f32x4){0.f, 0.f, 0.f, 0.f};
            e0 = __builtin_amdgcn_mfma_f32_16x16x32_bf16(WO[g4], OB0, e0, 0, 0, 0);
            e1 = __builtin_amdgcn_mfma_f32_16x16x32_bf16(WO[g4], OB1, e1, 0, 0, 0);
#pragma unroll
            for (int r = 0; r < 4; r++) {
                int cc = g4 * 16 + q * 4 + r;
                size_t gi0 = (((size_t)(b * 64 + cc)) << 14) + nw + nl;
                out[gi0] = gam * e0[r] + x[gi0];
                size_t gi1 = gi0 + 16;
                out[gi1] = gam * e1[r] + x[gi1];
            }
        }
    }
}

extern "C" void kernel_launch(void* const* d_in, const int* in_sizes, int n_in,
                              void* d_out, int out_size, void* d_ws, size_t ws_size,
                              hipStream_t stream) {
    const float* x       = (const float*)d_in[0];
    const float* w_theta = (const float*)d_in[1];
    const float* w_phi   = (const float*)d_in[2];
    const float* w_g     = (const float*)d_in[3];
    const float* w_o     = (const float*)d_in[4];
    const float* gamma   = (const float*)d_in[5];
    float* out = (float*)d_out;

    __hip_bfloat16* thG = (__hip_bfloat16*)d_ws;        // 4*16384*8 = 1 MB
    __hip_bfloat16* phG = thG + 524288;                 // 4*4096*8  = 256 KB
    __hip_bfloat16* gG  = phG + 131072;                 // 4*32*4096 = 1 MB

    proj_kernel<<<512, 256, 0, stream>>>(x, w_theta, w_phi, w_g, thG, phG, gG);
    attn_kernel<<<512, 512, 0, stream>>>(thG, phG, gG, w_o, gamma, x, out);
}